// Round 19
// baseline (81.087 us; speedup 1.0000x reference)
//
#include <hip/hip_runtime.h>
#include <hip/hip_bf16.h>

typedef unsigned int u32;
typedef unsigned short u16;
typedef __attribute__((ext_vector_type(8))) short bf16x8;   // 8 bf16 in 4 VGPRs
typedef __attribute__((ext_vector_type(4))) float f32x4;

#define NPIX 110592            // 48^3
#define NTILES 1728            // NPIX/64 per batch
#define K1_BLOCKS 864          // each block: one 256-px group (4 tiles), b-aligned
#define K1_TPB 4
#define PART_STRIDE 4224       // 4096 ctx + 128 rowsum

// ws layout (4-byte slots)                       (ws = 256 MiB, ample)
#define WS_ATB   0             // 2*4096 u32 (packed bf16 pairs of A^T, bias/4 folded)
#define WS_P2    8192          // 16 slices x 4224 f32 (slice-partial ctx/rsum)
#define WS_XPK   75776         // 864 blocks x 8192 u32: packed-x images (28.3 MB)
#define WS_PART  7153664       // per-block ctx partials

union FragU { u32 u[4]; bf16x8 v; };

#define MFMA(a,b,c) __builtin_amdgcn_mfma_f32_16x16x32_bf16((a),(b),(c),0,0,0)

__device__ __forceinline__ void gll16(const float* g, float* l) {
    typedef const __attribute__((address_space(1))) unsigned int* gp_t;
    typedef __attribute__((address_space(3))) unsigned int* lp_t;
    __builtin_amdgcn_global_load_lds((gp_t)g, (lp_t)l, 16, 0, 0);
}
// pk2 via compiler casts -> v_cvt_pk_bf16_f32 (RNE; m240: casts beat manual)
__device__ __forceinline__ u32 pk2(float a, float b) {
    union { __hip_bfloat162 h2; u32 u; } cv;
    cv.h2.x = __float2bfloat16(a);
    cv.h2.y = __float2bfloat16(b);
    return cv.u;
}

// ---------------- K1: k,v GEMM (MFMA) + ctx/rowsum (MFMA) ----------------
// R17 kernel verbatim (W bf16-hi only; kvb-free; exports packed x image).
__global__ __launch_bounds__(256, 3)
void k1_ctx(const float* __restrict__ x, const float* __restrict__ wq,
            float* __restrict__ ws, int usePart, int R) {
    __shared__ u32 xbh[256 * 32];      // [px][cpair hi], swizzled, 32 KB
    const int blk = blockIdx.x;
    const int p   = threadIdx.x & 63;
    const int og  = __builtin_amdgcn_readfirstlane(threadIdx.x >> 6);
    const int b   = blk / (K1_BLOCKS / 2);
    const int q   = p >> 4;
    const int l15 = p & 15;
    const int yv  = (p & 7) << 2;
    const float* xg = x + (long)b * 64 * NPIX;
    float* part = ws + WS_PART;

    FragU wh[4][2];
    #pragma unroll
    for (int mi = 0; mi < 4; ++mi)
        #pragma unroll
        for (int ks = 0; ks < 2; ++ks) {
            const int kvrow = (mi < 2) ? (og * 32 + mi * 16) : (128 + og * 32 + (mi - 2) * 16);
            const int row = 128 + kvrow + l15;
            const float* wp = wq + row * 64 + ks * 32 + q * 4;
            float4 f0 = *(const float4*)wp;
            float4 f1 = *(const float4*)(wp + 16);
            wh[mi][ks].u[0] = pk2(f0.x, f0.y);
            wh[mi][ks].u[1] = pk2(f0.z, f0.w);
            wh[mi][ks].u[2] = pk2(f1.x, f1.y);
            wh[mi][ks].u[3] = pk2(f1.z, f1.w);
        }

    FragU ones;
    #pragma unroll
    for (int i = 0; i < 4; ++i) ones.u[i] = 0x3F803F80u;

    f32x4 cc[2][2], rsa[2];
    #pragma unroll
    for (int mi = 0; mi < 2; ++mi) {
        #pragma unroll
        for (int ni = 0; ni < 2; ++ni) cc[mi][ni] = (f32x4)0.f;
        rsa[mi] = (f32x4)0.f;
    }

    const long i0g = (long)(blk * K1_TPB - b * NTILES) * 64;   // group px start
    #pragma unroll
    for (int ch = 0; ch < 2; ++ch) {
        f32x4 xl4[8];
        const float* xr = xg + (long)(og * 16 + ch * 8) * NPIX + i0g + 4 * p;
        #pragma unroll
        for (int i = 0; i < 8; ++i) xl4[i] = *(const f32x4*)(xr + (long)i * NPIX);
        #pragma unroll
        for (int j = 0; j < 4; ++j) {
            const int px = 4 * p + j;
            const int yy = (px & 7) << 2;
            u32 h[4];
            #pragma unroll
            for (int w = 0; w < 4; ++w) h[w] = pk2(xl4[2 * w][j], xl4[2 * w + 1][j]);
            const int sA = (og * 8 + ch * 4) ^ yy;
            *(uint4*)&xbh[px * 32 + sA] = make_uint4(h[0], h[1], h[2], h[3]);
        }
    }
    __syncthreads();               // xbh ready for all 4 tiles (read-only after)

    // export packed image for k3 (LDS round-trip -> linear coalesced stores)
    {
        u32* xpk = (u32*)ws + WS_XPK + (long)blk * 8192;
        #pragma unroll
        for (int i = 0; i < 8; ++i) {
            const int idx = i * 1024 + threadIdx.x * 4;
            uint4 v = *(const uint4*)&xbh[idx];
            *(uint4*)&xpk[idx] = v;
        }
    }

    #pragma unroll 1
    for (int tt = 0; tt < K1_TPB; ++tt) {
        #pragma unroll
        for (int ksp = 0; ksp < 2; ++ksp) {
            f32x4 acc[4][2];
            #pragma unroll
            for (int ni2 = 0; ni2 < 2; ++ni2) {
                const int ni = ksp * 2 + ni2;
                const int rb = (tt * 64 + ni * 16 + l15) * 32;
                FragU bh[2];
                #pragma unroll
                for (int ks = 0; ks < 2; ++ks) {
                    const int c0 = (ks * 16 + 2 * q) ^ yv;
                    const int c1 = (ks * 16 + 2 * q + 8) ^ yv;
                    uint2 t0 = *(const uint2*)&xbh[rb + c0];
                    uint2 t1 = *(const uint2*)&xbh[rb + c1];
                    bh[ks].u[0] = t0.x; bh[ks].u[1] = t0.y;
                    bh[ks].u[2] = t1.x; bh[ks].u[3] = t1.y;
                }
                #pragma unroll
                for (int mi = 0; mi < 4; ++mi) {
                    f32x4 a = (f32x4)0.f;
                    #pragma unroll
                    for (int ks = 0; ks < 2; ++ks)
                        a = MFMA(bh[ks].v, wh[mi][ks].v, a);
                    acc[mi][ni2] = a;
                }
            }
            FragU ak[2], av[2];
            #pragma unroll
            for (int m2 = 0; m2 < 2; ++m2) {
                float e0[4], e1[4];
                #pragma unroll
                for (int j = 0; j < 4; ++j) {
                    e0[j] = __expf(acc[m2][0][j]);
                    e1[j] = __expf(acc[m2][1][j]);
                }
                ak[m2].u[0] = pk2(e0[0], e0[1]);
                ak[m2].u[1] = pk2(e0[2], e0[3]);
                ak[m2].u[2] = pk2(e1[0], e1[1]);
                ak[m2].u[3] = pk2(e1[2], e1[3]);
                av[m2].u[0] = pk2(acc[2 + m2][0][0], acc[2 + m2][0][1]);
                av[m2].u[1] = pk2(acc[2 + m2][0][2], acc[2 + m2][0][3]);
                av[m2].u[2] = pk2(acc[2 + m2][1][0], acc[2 + m2][1][1]);
                av[m2].u[3] = pk2(acc[2 + m2][1][2], acc[2 + m2][1][3]);
            }
            #pragma unroll
            for (int mi = 0; mi < 2; ++mi) {
                #pragma unroll
                for (int nj = 0; nj < 2; ++nj)
                    cc[mi][nj] = MFMA(ak[mi].v, av[nj].v, cc[mi][nj]);
                rsa[mi] = MFMA(ak[mi].v, ones.v, rsa[mi]);
            }
        }
    }

    if (usePart) {
        float* pp = part + (long)blk * PART_STRIDE;
        #pragma unroll
        for (int mi = 0; mi < 2; ++mi)
            #pragma unroll
            for (int ni = 0; ni < 2; ++ni)
                #pragma unroll
                for (int j = 0; j < 4; ++j)
                    pp[og * 1024 + (mi * 16 + q * 4 + j) * 32 + ni * 16 + l15] = cc[mi][ni][j];
        if (l15 == 0) {
            #pragma unroll
            for (int mi = 0; mi < 2; ++mi)
                #pragma unroll
                for (int j = 0; j < 4; ++j)
                    pp[4096 + og * 32 + mi * 16 + q * 4 + j] = rsa[mi][j];
        }
    } else {
        float* pp = part + (long)(b * R + (blk % R)) * PART_STRIDE;
        #pragma unroll
        for (int mi = 0; mi < 2; ++mi)
            #pragma unroll
            for (int ni = 0; ni < 2; ++ni)
                #pragma unroll
                for (int j = 0; j < 4; ++j)
                    atomicAdd(&pp[og * 1024 + (mi * 16 + q * 4 + j) * 32 + ni * 16 + l15], cc[mi][ni][j]);
        if (l15 == 0) {
            #pragma unroll
            for (int mi = 0; mi < 2; ++mi)
                #pragma unroll
                for (int j = 0; j < 4; ++j)
                    atomicAdd(&pp[4096 + og * 32 + mi * 16 + q * 4 + j], rsa[mi][j]);
        }
    }
}

// ---------------- K1b: reduce partials -> 16 slice-partials (no atomics) --
__global__ __launch_bounds__(128)
void k1b_reduce(float* __restrict__ ws, int PB) {
    const int S = 8;
    const int chunk = blockIdx.x % 33;
    const int rem   = blockIdx.x / 33;
    const int b     = rem & 1;
    const int slice = rem >> 1;
    const int j = chunk * 128 + threadIdx.x;       // [0, 4224)
    const int PBh = PB >> 1;
    const float* part = ws + WS_PART;
    float s = 0.f;
    for (int pi = b * PBh + slice; pi < (b + 1) * PBh; pi += S)
        s += part[(long)pi * PART_STRIDE + j];
    ws[WS_P2 + (long)(b * S + slice) * PART_STRIDE + j] = s;
}

// ---------------- K2: ATb[up][o] (bias/4 folded); 16 blocks --------------
__global__ __launch_bounds__(256)
void k2_prepA(const float* __restrict__ wout, const float* __restrict__ bout,
              float* __restrict__ ws) {
    __shared__ float wo[64 * 129];
    __shared__ float ct[4096];
    __shared__ float rsum[128];
    const int b   = blockIdx.x >> 3;
    const int jb  = blockIdx.x & 7;
    const int tid = threadIdx.x;
    for (int i = tid; i < 8192; i += 256) wo[(i >> 7) * 129 + (i & 127)] = wout[i];
    for (int i = tid; i < 4096; i += 256) {
        float s = 0.f;
        #pragma unroll
        for (int s8 = 0; s8 < 8; ++s8)
            s += ws[WS_P2 + (long)(b * 8 + s8) * PART_STRIDE + i];
        ct[i] = s;
    }
    if (tid < 128) {
        float s = 0.f;
        #pragma unroll
        for (int s8 = 0; s8 < 8; ++s8)
            s += ws[WS_P2 + (long)(b * 8 + s8) * PART_STRIDE + 4096 + tid];
        rsum[tid] = s;
    }
    __syncthreads();
    u32* atb = (u32*)ws + WS_ATB + b * 4096;
    const int o  = tid & 63;
    const int ug = tid >> 6;
    const float bo4 = 0.25f * bout[o];   // Σ_head qsm = 1 per head, 4 heads
    #pragma unroll
    for (int i = 0; i < 2; ++i) {
        const int up = jb * 8 + ug * 2 + i;
        const int hc0 = 2 * up, hc1 = 2 * up + 1;
        const int hh = hc0 >> 5;
        const int c0 = hc0 & 31, c1 = hc1 & 31;
        float s0 = 0.f, s1 = 0.f;
        #pragma unroll
        for (int d = 0; d < 32; ++d) {
            const float w = wo[o * 129 + hh * 32 + d];
            s0 = fmaf(w, ct[hh * 1024 + c0 * 32 + d], s0);
            s1 = fmaf(w, ct[hh * 1024 + c1 * 32 + d], s1);
        }
        atb[up * 64 + o] = pk2(s0 / rsum[hc0] + bo4, s1 / rsum[hc1] + bo4);
    }
}

// ---------------- K3: q GEMM + in-reg softmax + A@q — fully wave-private --
// R19 = R18 with the phase-1 operand order FIXED: A=wh, B=bh -> D[o][px]
// (lane: px = og*16+l15, rows mi*16+q*4+j). Softmax in-lane-8 + shfl over
// q-bits (16/32) as in R17; lane's own normalized values ARE the phase-3
// B-frag elements. qb LDS + both per-tile barriers deleted.
__global__ __launch_bounds__(256, 2)
void k3_out(const float* __restrict__ x, const float* __restrict__ wq,
            const float* __restrict__ bout, const float* __restrict__ wsf,
            float* __restrict__ out) {
    __shared__ u32 xbh[256 * 32];      // [px][cpair hi], swizzled, 32 KB
    const int blk = blockIdx.x;
    const int p   = threadIdx.x & 63;
    const int og  = __builtin_amdgcn_readfirstlane(threadIdx.x >> 6);
    const int b   = blk / (K1_BLOCKS / 2);
    const int q   = p >> 4;
    const int l15 = p & 15;
    const int yv  = (p & 7) << 2;
    (void)x; (void)bout;

    // stage packed x image (async) — wave og stages its 8 KB quarter
    {
        const u32* xpk = (const u32*)wsf + WS_XPK + (long)blk * 8192;
        #pragma unroll
        for (int i = 0; i < 8; ++i) {
            const int o32 = og * 2048 + i * 256;       // u32 offset of 1KB chunk
            gll16((const float*)&xpk[o32 + 4 * p], (float*)&xbh[o32]);
        }
    }

    // W frags: ALL 128 q rows, bf16-hi only (8 blocks x 2 ks)
    FragU wh[8][2];
    #pragma unroll
    for (int mi = 0; mi < 8; ++mi)
        #pragma unroll
        for (int ks = 0; ks < 2; ++ks) {
            const int row = mi * 16 + l15;
            const float* wp = wq + row * 64 + ks * 32 + q * 4;
            float4 f0 = *(const float4*)wp;
            float4 f1 = *(const float4*)(wp + 16);
            wh[mi][ks].u[0] = pk2(f0.x, f0.y);
            wh[mi][ks].u[1] = pk2(f0.z, f0.w);
            wh[mi][ks].u[2] = pk2(f1.x, f1.y);
            wh[mi][ks].u[3] = pk2(f1.z, f1.w);
        }

    // ATb frags: ALL 4 o-blocks x 4 ks (bias folded in k2)
    const u32* atb = (const u32*)wsf + WS_ATB + b * 4096;
    FragU af[4][4];
    #pragma unroll
    for (int ob = 0; ob < 4; ++ob)
        #pragma unroll
        for (int ks = 0; ks < 4; ++ks) {
            const int up0 = ks * 16 + 2 * q;
            const int o   = ob * 16 + l15;
            af[ob][ks].u[0] = atb[(up0)     * 64 + o];
            af[ob][ks].u[1] = atb[(up0 + 1) * 64 + o];
            af[ob][ks].u[2] = atb[(up0 + 8) * 64 + o];
            af[ob][ks].u[3] = atb[(up0 + 9) * 64 + o];
        }

    asm volatile("s_waitcnt vmcnt(0)" ::: "memory");
    __syncthreads();               // xbh staged by all waves (read-only after)

    const long i0g = (long)(blk * K1_TPB - b * NTILES) * 64;
    #pragma unroll 1
    for (int tt = 0; tt < K1_TPB; ++tt) {
        const long i0 = i0g + tt * 64;

        // phase 1: all 128 q-rows for this wave's px-quarter (ni = og)
        FragU bh[2];
        {
            const int rb = (tt * 64 + og * 16 + l15) * 32;
            #pragma unroll
            for (int ks = 0; ks < 2; ++ks) {
                const int c0 = (ks * 16 + 2 * q) ^ yv;
                const int c1 = (ks * 16 + 2 * q + 8) ^ yv;
                uint2 t0 = *(const uint2*)&xbh[rb + c0];
                uint2 t1 = *(const uint2*)&xbh[rb + c1];
                bh[ks].u[0] = t0.x; bh[ks].u[1] = t0.y;
                bh[ks].u[2] = t1.x; bh[ks].u[3] = t1.y;
            }
        }
        f32x4 acc[8];
        #pragma unroll
        for (int mi = 0; mi < 8; ++mi) {
            f32x4 a = (f32x4)0.f;
            #pragma unroll
            for (int ks = 0; ks < 2; ++ks)
                a = MFMA(wh[mi][ks].v, bh[ks].v, a);   // A=W, B=x -> D[o][px]
            acc[mi] = a;
        }

        // phase 2: 4 per-head softmaxes (in-lane 8 vals + shfl 16/32), then
        // pack bq[ks] from the lane's OWN normalized values.
        FragU bq[4];
        #pragma unroll
        for (int h = 0; h < 4; ++h) {
            float mx = acc[2 * h][0];
            #pragma unroll
            for (int j = 1; j < 4; ++j) mx = fmaxf(mx, acc[2 * h][j]);
            #pragma unroll
            for (int j = 0; j < 4; ++j) mx = fmaxf(mx, acc[2 * h + 1][j]);
            mx = fmaxf(mx, __shfl_xor(mx, 16));
            mx = fmaxf(mx, __shfl_xor(mx, 32));
            float e0[4], e1[4], sm = 0.f;
            #pragma unroll
            for (int j = 0; j < 4; ++j) { e0[j] = __expf(acc[2 * h][j] - mx); sm += e0[j]; }
            #pragma unroll
            for (int j = 0; j < 4; ++j) { e1[j] = __expf(acc[2 * h + 1][j] - mx); sm += e1[j]; }
            sm += __shfl_xor(sm, 16);
            sm += __shfl_xor(sm, 32);
            const float inv = 1.0f / sm;
            bq[h].u[0] = pk2(e0[0] * inv, e0[1] * inv);
            bq[h].u[1] = pk2(e0[2] * inv, e0[3] * inv);
            bq[h].u[2] = pk2(e1[0] * inv, e1[1] * inv);
            bq[h].u[3] = pk2(e1[2] * inv, e1[3] * inv);
        }

        // phase 3: out[all 64 o][own 16 px] = A^T qsm  (bias already in A)
        #pragma unroll
        for (int ob = 0; ob < 4; ++ob) {
            f32x4 a3 = (f32x4)0.f;
            #pragma unroll
            for (int ks = 0; ks < 4; ++ks)
                a3 = MFMA(af[ob][ks].v, bq[ks].v, a3);
            float* op = out + ((long)b * 64 + ob * 16 + q * 4) * NPIX + i0 + og * 16 + l15;
            #pragma unroll
            for (int j = 0; j < 4; ++j)
                op[(long)j * NPIX] = a3[j];
        }
    }
}

extern "C" void kernel_launch(void* const* d_in, const int* in_sizes, int n_in,
                              void* d_out, int out_size, void* d_ws, size_t ws_size,
                              hipStream_t stream) {
    (void)in_sizes; (void)n_in; (void)out_size;
    const float* x     = (const float*)d_in[0];
    const float* w_qkv = (const float*)d_in[1];
    const float* w_out = (const float*)d_in[2];
    const float* b_out = (const float*)d_in[3];
    float* out = (float*)d_out;
    float* ws  = (float*)d_ws;

    const size_t need_part = ((size_t)WS_PART + (size_t)K1_BLOCKS * PART_STRIDE) * 4;
    const int usePart = (ws_size >= need_part) ? 1 : 0;
    int R = 8;
    const size_t need_r8 = ((size_t)WS_PART + (size_t)2 * 8 * PART_STRIDE) * 4;
    if (!usePart && ws_size < need_r8) R = 1;
    const int PB = usePart ? K1_BLOCKS : 2 * R;
    float* part = ws + WS_PART;

    if (!usePart)
        hipMemsetAsync(part, 0, (size_t)PB * PART_STRIDE * 4, stream);
    hipLaunchKernelGGL(k1_ctx, dim3(K1_BLOCKS), dim3(256), 0, stream,
                       x, w_qkv, ws, usePart, R);
    hipLaunchKernelGGL(k1b_reduce, dim3(528), dim3(128), 0, stream, ws, PB);
    hipLaunchKernelGGL(k2_prepA, dim3(16), dim3(256), 0, stream, w_out, b_out, ws);
    hipLaunchKernelGGL(k3_out, dim3(K1_BLOCKS), dim3(256), 0, stream,
                       x, w_qkv, b_out, ws, out);
}

// Round 20
// 75.395 us; speedup vs baseline: 1.0755x; 1.0755x over previous
//
#include <hip/hip_runtime.h>
#include <hip/hip_bf16.h>

typedef unsigned int u32;
typedef unsigned short u16;
typedef __attribute__((ext_vector_type(8))) short bf16x8;   // 8 bf16 in 4 VGPRs
typedef __attribute__((ext_vector_type(4))) float f32x4;

#define NPIX 110592            // 48^3
#define NTILES 1728            // NPIX/64 per batch
#define K1_BLOCKS 864          // each block: one 256-px group (4 tiles), b-aligned
#define K1_TPB 4
#define PART_STRIDE 4224       // 4096 ctx + 128 rowsum

// ws layout (4-byte slots)                       (ws = 256 MiB, ample)
#define WS_ATB   0             // 2*4096 u32 (packed bf16 pairs of A^T)
#define WS_P2    8192          // 16 slices x 4224 f32 (slice-partial ctx/rsum)
#define WS_XPK   75776         // 864 blocks x 8192 u32: packed-x images (28.3 MB)
#define WS_PART  7153664       // per-block ctx partials

union FragU { u32 u[4]; bf16x8 v; };

#define MFMA(a,b,c) __builtin_amdgcn_mfma_f32_16x16x32_bf16((a),(b),(c),0,0,0)

__device__ __forceinline__ void gll16(const float* g, float* l) {
    typedef const __attribute__((address_space(1))) unsigned int* gp_t;
    typedef __attribute__((address_space(3))) unsigned int* lp_t;
    __builtin_amdgcn_global_load_lds((gp_t)g, (lp_t)l, 16, 0, 0);
}
// pk2 via compiler casts -> v_cvt_pk_bf16_f32 (RNE; m240: casts beat manual)
__device__ __forceinline__ u32 pk2(float a, float b) {
    union { __hip_bfloat162 h2; u32 u; } cv;
    cv.h2.x = __float2bfloat16(a);
    cv.h2.y = __float2bfloat16(b);
    return cv.u;
}

// ---------------- K1: k,v GEMM (MFMA) + ctx/rowsum (MFMA) ----------------
// W fragments bf16-hi only; kvb-free (reg-direct phase1->phase2); exports
// the packed x image to WS_XPK for k3's reuse.
__global__ __launch_bounds__(256, 3)
void k1_ctx(const float* __restrict__ x, const float* __restrict__ wq,
            float* __restrict__ ws, int usePart, int R) {
    __shared__ u32 xbh[256 * 32];      // [px][cpair hi], swizzled, 32 KB
    const int blk = blockIdx.x;
    const int p   = threadIdx.x & 63;
    const int og  = __builtin_amdgcn_readfirstlane(threadIdx.x >> 6);
    const int b   = blk / (K1_BLOCKS / 2);
    const int q   = p >> 4;
    const int l15 = p & 15;
    const int yv  = (p & 7) << 2;
    const float* xg = x + (long)b * 64 * NPIX;
    float* part = ws + WS_PART;

    FragU wh[4][2];
    #pragma unroll
    for (int mi = 0; mi < 4; ++mi)
        #pragma unroll
        for (int ks = 0; ks < 2; ++ks) {
            const int kvrow = (mi < 2) ? (og * 32 + mi * 16) : (128 + og * 32 + (mi - 2) * 16);
            const int row = 128 + kvrow + l15;
            const float* wp = wq + row * 64 + ks * 32 + q * 4;
            float4 f0 = *(const float4*)wp;
            float4 f1 = *(const float4*)(wp + 16);
            wh[mi][ks].u[0] = pk2(f0.x, f0.y);
            wh[mi][ks].u[1] = pk2(f0.z, f0.w);
            wh[mi][ks].u[2] = pk2(f1.x, f1.y);
            wh[mi][ks].u[3] = pk2(f1.z, f1.w);
        }

    FragU ones;
    #pragma unroll
    for (int i = 0; i < 4; ++i) ones.u[i] = 0x3F803F80u;

    f32x4 cc[2][2], rsa[2];
    #pragma unroll
    for (int mi = 0; mi < 2; ++mi) {
        #pragma unroll
        for (int ni = 0; ni < 2; ++ni) cc[mi][ni] = (f32x4)0.f;
        rsa[mi] = (f32x4)0.f;
    }

    const long i0g = (long)(blk * K1_TPB - b * NTILES) * 64;   // group px start
    #pragma unroll
    for (int ch = 0; ch < 2; ++ch) {
        f32x4 xl4[8];
        const float* xr = xg + (long)(og * 16 + ch * 8) * NPIX + i0g + 4 * p;
        #pragma unroll
        for (int i = 0; i < 8; ++i) xl4[i] = *(const f32x4*)(xr + (long)i * NPIX);
        #pragma unroll
        for (int j = 0; j < 4; ++j) {
            const int px = 4 * p + j;
            const int yy = (px & 7) << 2;
            u32 h[4];
            #pragma unroll
            for (int w = 0; w < 4; ++w) h[w] = pk2(xl4[2 * w][j], xl4[2 * w + 1][j]);
            const int sA = (og * 8 + ch * 4) ^ yy;
            *(uint4*)&xbh[px * 32 + sA] = make_uint4(h[0], h[1], h[2], h[3]);
        }
    }
    __syncthreads();               // xbh ready for all 4 tiles (read-only after)

    // export packed image for k3 (LDS round-trip -> linear coalesced stores)
    {
        u32* xpk = (u32*)ws + WS_XPK + (long)blk * 8192;
        #pragma unroll
        for (int i = 0; i < 8; ++i) {
            const int idx = i * 1024 + threadIdx.x * 4;
            uint4 v = *(const uint4*)&xbh[idx];
            *(uint4*)&xpk[idx] = v;
        }
    }

    #pragma unroll 1
    for (int tt = 0; tt < K1_TPB; ++tt) {
        #pragma unroll
        for (int ksp = 0; ksp < 2; ++ksp) {
            f32x4 acc[4][2];
            #pragma unroll
            for (int ni2 = 0; ni2 < 2; ++ni2) {
                const int ni = ksp * 2 + ni2;
                const int rb = (tt * 64 + ni * 16 + l15) * 32;
                FragU bh[2];
                #pragma unroll
                for (int ks = 0; ks < 2; ++ks) {
                    const int c0 = (ks * 16 + 2 * q) ^ yv;
                    const int c1 = (ks * 16 + 2 * q + 8) ^ yv;
                    uint2 t0 = *(const uint2*)&xbh[rb + c0];
                    uint2 t1 = *(const uint2*)&xbh[rb + c1];
                    bh[ks].u[0] = t0.x; bh[ks].u[1] = t0.y;
                    bh[ks].u[2] = t1.x; bh[ks].u[3] = t1.y;
                }
                #pragma unroll
                for (int mi = 0; mi < 4; ++mi) {
                    f32x4 a = (f32x4)0.f;
                    #pragma unroll
                    for (int ks = 0; ks < 2; ++ks)
                        a = MFMA(bh[ks].v, wh[mi][ks].v, a);
                    acc[mi][ni2] = a;
                }
            }
            FragU ak[2], av[2];
            #pragma unroll
            for (int m2 = 0; m2 < 2; ++m2) {
                float e0[4], e1[4];
                #pragma unroll
                for (int j = 0; j < 4; ++j) {
                    e0[j] = __expf(acc[m2][0][j]);
                    e1[j] = __expf(acc[m2][1][j]);
                }
                ak[m2].u[0] = pk2(e0[0], e0[1]);
                ak[m2].u[1] = pk2(e0[2], e0[3]);
                ak[m2].u[2] = pk2(e1[0], e1[1]);
                ak[m2].u[3] = pk2(e1[2], e1[3]);
                av[m2].u[0] = pk2(acc[2 + m2][0][0], acc[2 + m2][0][1]);
                av[m2].u[1] = pk2(acc[2 + m2][0][2], acc[2 + m2][0][3]);
                av[m2].u[2] = pk2(acc[2 + m2][1][0], acc[2 + m2][1][1]);
                av[m2].u[3] = pk2(acc[2 + m2][1][2], acc[2 + m2][1][3]);
            }
            #pragma unroll
            for (int mi = 0; mi < 2; ++mi) {
                #pragma unroll
                for (int nj = 0; nj < 2; ++nj)
                    cc[mi][nj] = MFMA(ak[mi].v, av[nj].v, cc[mi][nj]);
                rsa[mi] = MFMA(ak[mi].v, ones.v, rsa[mi]);
            }
        }
    }

    if (usePart) {
        float* pp = part + (long)blk * PART_STRIDE;
        #pragma unroll
        for (int mi = 0; mi < 2; ++mi)
            #pragma unroll
            for (int ni = 0; ni < 2; ++ni)
                #pragma unroll
                for (int j = 0; j < 4; ++j)
                    pp[og * 1024 + (mi * 16 + q * 4 + j) * 32 + ni * 16 + l15] = cc[mi][ni][j];
        if (l15 == 0) {
            #pragma unroll
            for (int mi = 0; mi < 2; ++mi)
                #pragma unroll
                for (int j = 0; j < 4; ++j)
                    pp[4096 + og * 32 + mi * 16 + q * 4 + j] = rsa[mi][j];
        }
    } else {
        float* pp = part + (long)(b * R + (blk % R)) * PART_STRIDE;
        #pragma unroll
        for (int mi = 0; mi < 2; ++mi)
            #pragma unroll
            for (int ni = 0; ni < 2; ++ni)
                #pragma unroll
                for (int j = 0; j < 4; ++j)
                    atomicAdd(&pp[og * 1024 + (mi * 16 + q * 4 + j) * 32 + ni * 16 + l15], cc[mi][ni][j]);
        if (l15 == 0) {
            #pragma unroll
            for (int mi = 0; mi < 2; ++mi)
                #pragma unroll
                for (int j = 0; j < 4; ++j)
                    atomicAdd(&pp[4096 + og * 32 + mi * 16 + q * 4 + j], rsa[mi][j]);
        }
    }
}

// ---------------- K1b: reduce partials -> 16 slice-partials (no atomics) --
__global__ __launch_bounds__(128)
void k1b_reduce(float* __restrict__ ws, int PB) {
    const int S = 8;
    const int chunk = blockIdx.x % 33;
    const int rem   = blockIdx.x / 33;
    const int b     = rem & 1;
    const int slice = rem >> 1;
    const int j = chunk * 128 + threadIdx.x;       // [0, 4224)
    const int PBh = PB >> 1;
    const float* part = ws + WS_PART;
    float s = 0.f;
    for (int pi = b * PBh + slice; pi < (b + 1) * PBh; pi += S)
        s += part[(long)pi * PART_STRIDE + j];
    ws[WS_P2 + (long)(b * S + slice) * PART_STRIDE + j] = s;
}

// ---------------- K2: ATb[up][o]; 16 blocks (8 per b), sums 8 slices -----
__global__ __launch_bounds__(256)
void k2_prepA(const float* __restrict__ wout, float* __restrict__ ws) {
    __shared__ float wo[64 * 129];
    __shared__ float ct[4096];
    __shared__ float rsum[128];
    const int b   = blockIdx.x >> 3;
    const int jb  = blockIdx.x & 7;
    const int tid = threadIdx.x;
    for (int i = tid; i < 8192; i += 256) wo[(i >> 7) * 129 + (i & 127)] = wout[i];
    for (int i = tid; i < 4096; i += 256) {
        float s = 0.f;
        #pragma unroll
        for (int s8 = 0; s8 < 8; ++s8)
            s += ws[WS_P2 + (long)(b * 8 + s8) * PART_STRIDE + i];
        ct[i] = s;
    }
    if (tid < 128) {
        float s = 0.f;
        #pragma unroll
        for (int s8 = 0; s8 < 8; ++s8)
            s += ws[WS_P2 + (long)(b * 8 + s8) * PART_STRIDE + 4096 + tid];
        rsum[tid] = s;
    }
    __syncthreads();
    u32* atb = (u32*)ws + WS_ATB + b * 4096;
    const int o  = tid & 63;
    const int ug = tid >> 6;
    #pragma unroll
    for (int i = 0; i < 2; ++i) {
        const int up = jb * 8 + ug * 2 + i;
        const int hc0 = 2 * up, hc1 = 2 * up + 1;
        const int hh = hc0 >> 5;
        const int c0 = hc0 & 31, c1 = hc1 & 31;
        float s0 = 0.f, s1 = 0.f;
        #pragma unroll
        for (int d = 0; d < 32; ++d) {
            const float w = wo[o * 129 + hh * 32 + d];
            s0 = fmaf(w, ct[hh * 1024 + c0 * 32 + d], s0);
            s1 = fmaf(w, ct[hh * 1024 + c1 * 32 + d], s1);
        }
        atb[up * 64 + o] = pk2(s0 / rsum[hc0], s1 / rsum[hc1]);
    }
}

// ---------------- K3: q GEMM (MFMA) + in-reg softmax + A@q (MFMA) --------
// W fragments bf16-hi only; staging = global_load_lds of k1's packed image.
__global__ __launch_bounds__(256, 3)
void k3_out(const float* __restrict__ x, const float* __restrict__ wq,
            const float* __restrict__ bout, const float* __restrict__ wsf,
            float* __restrict__ out) {
    __shared__ u32 xbh[256 * 32];      // [px][cpair hi], swizzled, 32 KB
    __shared__ u16 qb[64 * 128];       // [px][hc] bf16, swizzled, 16 KB
    const int blk = blockIdx.x;
    const int p   = threadIdx.x & 63;
    const int og  = __builtin_amdgcn_readfirstlane(threadIdx.x >> 6);
    const int b   = blk / (K1_BLOCKS / 2);
    const int q   = p >> 4;
    const int l15 = p & 15;
    const int yv  = (p & 7) << 2;
    (void)x;

    // stage packed x image (async) — wave og stages its 8 KB quarter
    {
        const u32* xpk = (const u32*)wsf + WS_XPK + (long)blk * 8192;
        #pragma unroll
        for (int i = 0; i < 8; ++i) {
            const int o32 = og * 2048 + i * 256;       // u32 offset of 1KB chunk
            gll16((const float*)&xpk[o32 + 4 * p], (float*)&xbh[o32]);
        }
    }

    // W frags: q rows og*32..+32, bf16-hi only (once per block)
    FragU wh[2][2];
    #pragma unroll
    for (int mi = 0; mi < 2; ++mi)
        #pragma unroll
        for (int ks = 0; ks < 2; ++ks) {
            const int row = og * 32 + mi * 16 + l15;
            const float* wp = wq + row * 64 + ks * 32 + q * 4;
            float4 f0 = *(const float4*)wp;
            float4 f1 = *(const float4*)(wp + 16);
            wh[mi][ks].u[0] = pk2(f0.x, f0.y);
            wh[mi][ks].u[1] = pk2(f0.z, f0.w);
            wh[mi][ks].u[2] = pk2(f1.x, f1.y);
            wh[mi][ks].u[3] = pk2(f1.z, f1.w);
        }

    // ATb frags (per-b matrix, packed bf16 pairs) — once per block
    const u32* atb = (const u32*)wsf + WS_ATB + b * 4096;
    FragU af[4];
    #pragma unroll
    for (int ks = 0; ks < 4; ++ks) {
        const int up0 = ks * 16 + 2 * q;
        const int o   = og * 16 + l15;
        af[ks].u[0] = atb[(up0)     * 64 + o];
        af[ks].u[1] = atb[(up0 + 1) * 64 + o];
        af[ks].u[2] = atb[(up0 + 8) * 64 + o];
        af[ks].u[3] = atb[(up0 + 9) * 64 + o];
    }
    const float4 bias = *(const float4*)&bout[og * 16 + q * 4];

    asm volatile("s_waitcnt vmcnt(0)" ::: "memory");
    __syncthreads();               // xbh staged by all waves

    const long i0g = (long)(blk * K1_TPB - b * NTILES) * 64;
    #pragma unroll 1
    for (int tt = 0; tt < K1_TPB; ++tt) {
        const long i0 = i0g + tt * 64;

        // phase 1 + softmax, per px-block ni
        #pragma unroll
        for (int ni = 0; ni < 4; ++ni) {
            const int rb = (tt * 64 + ni * 16 + l15) * 32;
            FragU bh[2];
            #pragma unroll
            for (int ks = 0; ks < 2; ++ks) {
                const int c0 = (ks * 16 + 2 * q) ^ yv;
                const int c1 = (ks * 16 + 2 * q + 8) ^ yv;
                uint2 t0 = *(const uint2*)&xbh[rb + c0];
                uint2 t1 = *(const uint2*)&xbh[rb + c1];
                bh[ks].u[0] = t0.x; bh[ks].u[1] = t0.y;
                bh[ks].u[2] = t1.x; bh[ks].u[3] = t1.y;
            }
            f32x4 a0 = (f32x4)0.f, a1 = (f32x4)0.f;
            #pragma unroll
            for (int ks = 0; ks < 2; ++ks) {
                a0 = MFMA(wh[0][ks].v, bh[ks].v, a0);
                a1 = MFMA(wh[1][ks].v, bh[ks].v, a1);
            }
            // softmax over head og's 32 rows for this lane's px column
            float mx = a0[0];
            #pragma unroll
            for (int j = 1; j < 4; ++j) mx = fmaxf(mx, a0[j]);
            #pragma unroll
            for (int j = 0; j < 4; ++j) mx = fmaxf(mx, a1[j]);
            mx = fmaxf(mx, __shfl_xor(mx, 16));
            mx = fmaxf(mx, __shfl_xor(mx, 32));
            float e0[4], e1[4], sm = 0.f;
            #pragma unroll
            for (int j = 0; j < 4; ++j) { e0[j] = __expf(a0[j] - mx); sm += e0[j]; }
            #pragma unroll
            for (int j = 0; j < 4; ++j) { e1[j] = __expf(a1[j] - mx); sm += e1[j]; }
            sm += __shfl_xor(sm, 16);
            sm += __shfl_xor(sm, 32);
            const float inv = 1.0f / sm;
            const int px = ni * 16 + l15;
            const int Xq = (px & 7) << 3;          // u16-unit swizzle
            u32* qbw = (u32*)qb;
            const int b0 = (px * 128 + ((og * 32 + q * 4) ^ Xq)) >> 1;
            const int b1 = (px * 128 + ((og * 32 + 16 + q * 4) ^ Xq)) >> 1;
            *(uint2*)&qbw[b0] = make_uint2(pk2(e0[0] * inv, e0[1] * inv),
                                           pk2(e0[2] * inv, e0[3] * inv));
            *(uint2*)&qbw[b1] = make_uint2(pk2(e1[0] * inv, e1[1] * inv),
                                           pk2(e1[2] * inv, e1[3] * inv));
        }
        __syncthreads();               // qb ready

        // phase 3: out = A^T qsm + bias
        const u32* qb32 = (const u32*)qb;
        #pragma unroll
        for (int ni = 0; ni < 4; ++ni) {
            const int px = ni * 16 + l15;
            const int rb = px * 64;
            f32x4 a3 = (f32x4)0.f;
            #pragma unroll
            for (int ks = 0; ks < 4; ++ks) {
                const int c0 = (ks * 16 + 2 * q) ^ yv;
                const int c1 = (ks * 16 + 2 * q + 8) ^ yv;
                uint2 t0 = *(const uint2*)&qb32[rb + c0];
                uint2 t1 = *(const uint2*)&qb32[rb + c1];
                FragU bq;
                bq.u[0] = t0.x; bq.u[1] = t0.y; bq.u[2] = t1.x; bq.u[3] = t1.y;
                a3 = MFMA(af[ks].v, bq.v, a3);
            }
            #pragma unroll
            for (int j = 0; j < 4; ++j)
                out[((long)b * 64 + og * 16 + q * 4 + j) * NPIX + i0 + px] = a3[j] + bias[j];
        }
        __syncthreads();               // qb consumed before next tile's writes
    }
}

extern "C" void kernel_launch(void* const* d_in, const int* in_sizes, int n_in,
                              void* d_out, int out_size, void* d_ws, size_t ws_size,
                              hipStream_t stream) {
    (void)in_sizes; (void)n_in; (void)out_size;
    const float* x     = (const float*)d_in[0];
    const float* w_qkv = (const float*)d_in[1];
    const float* w_out = (const float*)d_in[2];
    const float* b_out = (const float*)d_in[3];
    float* out = (float*)d_out;
    float* ws  = (float*)d_ws;

    const size_t need_part = ((size_t)WS_PART + (size_t)K1_BLOCKS * PART_STRIDE) * 4;
    const int usePart = (ws_size >= need_part) ? 1 : 0;
    int R = 8;
    const size_t need_r8 = ((size_t)WS_PART + (size_t)2 * 8 * PART_STRIDE) * 4;
    if (!usePart && ws_size < need_r8) R = 1;
    const int PB = usePart ? K1_BLOCKS : 2 * R;
    float* part = ws + WS_PART;

    if (!usePart)
        hipMemsetAsync(part, 0, (size_t)PB * PART_STRIDE * 4, stream);
    hipLaunchKernelGGL(k1_ctx, dim3(K1_BLOCKS), dim3(256), 0, stream,
                       x, w_qkv, ws, usePart, R);
    hipLaunchKernelGGL(k1b_reduce, dim3(528), dim3(128), 0, stream, ws, PB);
    hipLaunchKernelGGL(k2_prepA, dim3(16), dim3(256), 0, stream, w_out, ws);
    hipLaunchKernelGGL(k3_out, dim3(K1_BLOCKS), dim3(256), 0, stream,
                       x, w_qkv, b_out, ws, out);
}

// Round 21
// 71.603 us; speedup vs baseline: 1.1325x; 1.0530x over previous
//
#include <hip/hip_runtime.h>
#include <hip/hip_bf16.h>

typedef unsigned int u32;
typedef unsigned short u16;
typedef __attribute__((ext_vector_type(8))) short bf16x8;   // 8 bf16 in 4 VGPRs
typedef __attribute__((ext_vector_type(4))) float f32x4;

#define NPIX 110592            // 48^3
#define NTILES 1728            // NPIX/64 per batch
#define K1_BLOCKS 864          // each block: one 256-px group (4 tiles), b-aligned
#define K1_TPB 4
#define PART_STRIDE 4224       // 4096 ctx + 128 rowsum
#define NSLICE 16              // k1b slices per batch (was 8)

// ws layout (4-byte slots)                       (ws = 256 MiB, ample)
#define WS_ATB   0             // 2*4096 u32 (packed bf16 pairs of A^T)
#define WS_P2    8192          // 32 slices x 4224 f32 (slice-partial ctx/rsum)
#define WS_XPK   143360        // 864 blocks x 8192 u32: packed-x images (28.3 MB)
#define WS_PART  7221248       // per-block ctx partials

union FragU { u32 u[4]; bf16x8 v; };

#define MFMA(a,b,c) __builtin_amdgcn_mfma_f32_16x16x32_bf16((a),(b),(c),0,0,0)

__device__ __forceinline__ void gll16(const float* g, float* l) {
    typedef const __attribute__((address_space(1))) unsigned int* gp_t;
    typedef __attribute__((address_space(3))) unsigned int* lp_t;
    __builtin_amdgcn_global_load_lds((gp_t)g, (lp_t)l, 16, 0, 0);
}
// pk2 via compiler casts -> v_cvt_pk_bf16_f32 (RNE; m240: casts beat manual)
__device__ __forceinline__ u32 pk2(float a, float b) {
    union { __hip_bfloat162 h2; u32 u; } cv;
    cv.h2.x = __float2bfloat16(a);
    cv.h2.y = __float2bfloat16(b);
    return cv.u;
}

// ---------------- K1: k,v GEMM (MFMA) + ctx/rowsum (MFMA) ----------------
// W fragments bf16-hi only; kvb-free (reg-direct phase1->phase2); exports
// the packed x image to WS_XPK for k3's reuse.
__global__ __launch_bounds__(256, 3)
void k1_ctx(const float* __restrict__ x, const float* __restrict__ wq,
            float* __restrict__ ws, int usePart, int R) {
    __shared__ u32 xbh[256 * 32];      // [px][cpair hi], swizzled, 32 KB
    const int blk = blockIdx.x;
    const int p   = threadIdx.x & 63;
    const int og  = __builtin_amdgcn_readfirstlane(threadIdx.x >> 6);
    const int b   = blk / (K1_BLOCKS / 2);
    const int q   = p >> 4;
    const int l15 = p & 15;
    const int yv  = (p & 7) << 2;
    const float* xg = x + (long)b * 64 * NPIX;
    float* part = ws + WS_PART;

    FragU wh[4][2];
    #pragma unroll
    for (int mi = 0; mi < 4; ++mi)
        #pragma unroll
        for (int ks = 0; ks < 2; ++ks) {
            const int kvrow = (mi < 2) ? (og * 32 + mi * 16) : (128 + og * 32 + (mi - 2) * 16);
            const int row = 128 + kvrow + l15;
            const float* wp = wq + row * 64 + ks * 32 + q * 4;
            float4 f0 = *(const float4*)wp;
            float4 f1 = *(const float4*)(wp + 16);
            wh[mi][ks].u[0] = pk2(f0.x, f0.y);
            wh[mi][ks].u[1] = pk2(f0.z, f0.w);
            wh[mi][ks].u[2] = pk2(f1.x, f1.y);
            wh[mi][ks].u[3] = pk2(f1.z, f1.w);
        }

    FragU ones;
    #pragma unroll
    for (int i = 0; i < 4; ++i) ones.u[i] = 0x3F803F80u;

    f32x4 cc[2][2], rsa[2];
    #pragma unroll
    for (int mi = 0; mi < 2; ++mi) {
        #pragma unroll
        for (int ni = 0; ni < 2; ++ni) cc[mi][ni] = (f32x4)0.f;
        rsa[mi] = (f32x4)0.f;
    }

    const long i0g = (long)(blk * K1_TPB - b * NTILES) * 64;   // group px start
    #pragma unroll
    for (int ch = 0; ch < 2; ++ch) {
        f32x4 xl4[8];
        const float* xr = xg + (long)(og * 16 + ch * 8) * NPIX + i0g + 4 * p;
        #pragma unroll
        for (int i = 0; i < 8; ++i) xl4[i] = *(const f32x4*)(xr + (long)i * NPIX);
        #pragma unroll
        for (int j = 0; j < 4; ++j) {
            const int px = 4 * p + j;
            const int yy = (px & 7) << 2;
            u32 h[4];
            #pragma unroll
            for (int w = 0; w < 4; ++w) h[w] = pk2(xl4[2 * w][j], xl4[2 * w + 1][j]);
            const int sA = (og * 8 + ch * 4) ^ yy;
            *(uint4*)&xbh[px * 32 + sA] = make_uint4(h[0], h[1], h[2], h[3]);
        }
    }
    __syncthreads();               // xbh ready for all 4 tiles (read-only after)

    // export packed image for k3 (LDS round-trip -> linear coalesced stores)
    {
        u32* xpk = (u32*)ws + WS_XPK + (long)blk * 8192;
        #pragma unroll
        for (int i = 0; i < 8; ++i) {
            const int idx = i * 1024 + threadIdx.x * 4;
            uint4 v = *(const uint4*)&xbh[idx];
            *(uint4*)&xpk[idx] = v;
        }
    }

    #pragma unroll 1
    for (int tt = 0; tt < K1_TPB; ++tt) {
        #pragma unroll
        for (int ksp = 0; ksp < 2; ++ksp) {
            f32x4 acc[4][2];
            #pragma unroll
            for (int ni2 = 0; ni2 < 2; ++ni2) {
                const int ni = ksp * 2 + ni2;
                const int rb = (tt * 64 + ni * 16 + l15) * 32;
                FragU bh[2];
                #pragma unroll
                for (int ks = 0; ks < 2; ++ks) {
                    const int c0 = (ks * 16 + 2 * q) ^ yv;
                    const int c1 = (ks * 16 + 2 * q + 8) ^ yv;
                    uint2 t0 = *(const uint2*)&xbh[rb + c0];
                    uint2 t1 = *(const uint2*)&xbh[rb + c1];
                    bh[ks].u[0] = t0.x; bh[ks].u[1] = t0.y;
                    bh[ks].u[2] = t1.x; bh[ks].u[3] = t1.y;
                }
                #pragma unroll
                for (int mi = 0; mi < 4; ++mi) {
                    f32x4 a = (f32x4)0.f;
                    #pragma unroll
                    for (int ks = 0; ks < 2; ++ks)
                        a = MFMA(bh[ks].v, wh[mi][ks].v, a);
                    acc[mi][ni2] = a;
                }
            }
            FragU ak[2], av[2];
            #pragma unroll
            for (int m2 = 0; m2 < 2; ++m2) {
                float e0[4], e1[4];
                #pragma unroll
                for (int j = 0; j < 4; ++j) {
                    e0[j] = __expf(acc[m2][0][j]);
                    e1[j] = __expf(acc[m2][1][j]);
                }
                ak[m2].u[0] = pk2(e0[0], e0[1]);
                ak[m2].u[1] = pk2(e0[2], e0[3]);
                ak[m2].u[2] = pk2(e1[0], e1[1]);
                ak[m2].u[3] = pk2(e1[2], e1[3]);
                av[m2].u[0] = pk2(acc[2 + m2][0][0], acc[2 + m2][0][1]);
                av[m2].u[1] = pk2(acc[2 + m2][0][2], acc[2 + m2][0][3]);
                av[m2].u[2] = pk2(acc[2 + m2][1][0], acc[2 + m2][1][1]);
                av[m2].u[3] = pk2(acc[2 + m2][1][2], acc[2 + m2][1][3]);
            }
            #pragma unroll
            for (int mi = 0; mi < 2; ++mi) {
                #pragma unroll
                for (int nj = 0; nj < 2; ++nj)
                    cc[mi][nj] = MFMA(ak[mi].v, av[nj].v, cc[mi][nj]);
                rsa[mi] = MFMA(ak[mi].v, ones.v, rsa[mi]);
            }
        }
    }

    if (usePart) {
        float* pp = part + (long)blk * PART_STRIDE;
        #pragma unroll
        for (int mi = 0; mi < 2; ++mi)
            #pragma unroll
            for (int ni = 0; ni < 2; ++ni)
                #pragma unroll
                for (int j = 0; j < 4; ++j)
                    pp[og * 1024 + (mi * 16 + q * 4 + j) * 32 + ni * 16 + l15] = cc[mi][ni][j];
        if (l15 == 0) {
            #pragma unroll
            for (int mi = 0; mi < 2; ++mi)
                #pragma unroll
                for (int j = 0; j < 4; ++j)
                    pp[4096 + og * 32 + mi * 16 + q * 4 + j] = rsa[mi][j];
        }
    } else {
        float* pp = part + (long)(b * R + (blk % R)) * PART_STRIDE;
        #pragma unroll
        for (int mi = 0; mi < 2; ++mi)
            #pragma unroll
            for (int ni = 0; ni < 2; ++ni)
                #pragma unroll
                for (int j = 0; j < 4; ++j)
                    atomicAdd(&pp[og * 1024 + (mi * 16 + q * 4 + j) * 32 + ni * 16 + l15], cc[mi][ni][j]);
        if (l15 == 0) {
            #pragma unroll
            for (int mi = 0; mi < 2; ++mi)
                #pragma unroll
                for (int j = 0; j < 4; ++j)
                    atomicAdd(&pp[4096 + og * 32 + mi * 16 + q * 4 + j], rsa[mi][j]);
        }
    }
}

// ---------------- K1b: reduce partials -> 32 slice-partials (no atomics) --
// R21: NSLICE=16 per b -> grid 1056, per-thread chain 27 loads (was 108).
__global__ __launch_bounds__(128)
void k1b_reduce(float* __restrict__ ws, int PB) {
    const int chunk = blockIdx.x % 33;
    const int rem   = blockIdx.x / 33;
    const int b     = rem & 1;
    const int slice = rem >> 1;                    // 0..NSLICE-1
    const int j = chunk * 128 + threadIdx.x;       // [0, 4224)
    const int PBh = PB >> 1;
    const float* part = ws + WS_PART;
    float s = 0.f;
    for (int pi = b * PBh + slice; pi < (b + 1) * PBh; pi += NSLICE)
        s += part[(long)pi * PART_STRIDE + j];
    ws[WS_P2 + (long)(b * NSLICE + slice) * PART_STRIDE + j] = s;
}

// ---------------- K2: ATb[up][o]; 16 blocks (8 per b), sums 16 slices ----
__global__ __launch_bounds__(256)
void k2_prepA(const float* __restrict__ wout, float* __restrict__ ws) {
    __shared__ float wo[64 * 129];
    __shared__ float ct[4096];
    __shared__ float rsum[128];
    const int b   = blockIdx.x >> 3;
    const int jb  = blockIdx.x & 7;
    const int tid = threadIdx.x;
    for (int i = tid; i < 8192; i += 256) wo[(i >> 7) * 129 + (i & 127)] = wout[i];
    for (int i = tid; i < 4096; i += 256) {
        float s = 0.f;
        #pragma unroll
        for (int s8 = 0; s8 < NSLICE; ++s8)
            s += ws[WS_P2 + (long)(b * NSLICE + s8) * PART_STRIDE + i];
        ct[i] = s;
    }
    if (tid < 128) {
        float s = 0.f;
        #pragma unroll
        for (int s8 = 0; s8 < NSLICE; ++s8)
            s += ws[WS_P2 + (long)(b * NSLICE + s8) * PART_STRIDE + 4096 + tid];
        rsum[tid] = s;
    }
    __syncthreads();
    u32* atb = (u32*)ws + WS_ATB + b * 4096;
    const int o  = tid & 63;
    const int ug = tid >> 6;
    #pragma unroll
    for (int i = 0; i < 2; ++i) {
        const int up = jb * 8 + ug * 2 + i;
        const int hc0 = 2 * up, hc1 = 2 * up + 1;
        const int hh = hc0 >> 5;
        const int c0 = hc0 & 31, c1 = hc1 & 31;
        float s0 = 0.f, s1 = 0.f;
        #pragma unroll
        for (int d = 0; d < 32; ++d) {
            const float w = wo[o * 129 + hh * 32 + d];
            s0 = fmaf(w, ct[hh * 1024 + c0 * 32 + d], s0);
            s1 = fmaf(w, ct[hh * 1024 + c1 * 32 + d], s1);
        }
        atb[up * 64 + o] = pk2(s0 / rsum[hc0], s1 / rsum[hc1]);
    }
}

// ---------------- K3: q GEMM (MFMA) + in-reg softmax + A@q (MFMA) --------
// W fragments bf16-hi only; staging = global_load_lds of k1's packed image.
__global__ __launch_bounds__(256, 3)
void k3_out(const float* __restrict__ x, const float* __restrict__ wq,
            const float* __restrict__ bout, const float* __restrict__ wsf,
            float* __restrict__ out) {
    __shared__ u32 xbh[256 * 32];      // [px][cpair hi], swizzled, 32 KB
    __shared__ u16 qb[64 * 128];       // [px][hc] bf16, swizzled, 16 KB
    const int blk = blockIdx.x;
    const int p   = threadIdx.x & 63;
    const int og  = __builtin_amdgcn_readfirstlane(threadIdx.x >> 6);
    const int b   = blk / (K1_BLOCKS / 2);
    const int q   = p >> 4;
    const int l15 = p & 15;
    const int yv  = (p & 7) << 2;
    (void)x;

    // stage packed x image (async) — wave og stages its 8 KB quarter
    {
        const u32* xpk = (const u32*)wsf + WS_XPK + (long)blk * 8192;
        #pragma unroll
        for (int i = 0; i < 8; ++i) {
            const int o32 = og * 2048 + i * 256;       // u32 offset of 1KB chunk
            gll16((const float*)&xpk[o32 + 4 * p], (float*)&xbh[o32]);
        }
    }

    // W frags: q rows og*32..+32, bf16-hi only (once per block)
    FragU wh[2][2];
    #pragma unroll
    for (int mi = 0; mi < 2; ++mi)
        #pragma unroll
        for (int ks = 0; ks < 2; ++ks) {
            const int row = og * 32 + mi * 16 + l15;
            const float* wp = wq + row * 64 + ks * 32 + q * 4;
            float4 f0 = *(const float4*)wp;
            float4 f1 = *(const float4*)(wp + 16);
            wh[mi][ks].u[0] = pk2(f0.x, f0.y);
            wh[mi][ks].u[1] = pk2(f0.z, f0.w);
            wh[mi][ks].u[2] = pk2(f1.x, f1.y);
            wh[mi][ks].u[3] = pk2(f1.z, f1.w);
        }

    // ATb frags (per-b matrix, packed bf16 pairs) — once per block
    const u32* atb = (const u32*)wsf + WS_ATB + b * 4096;
    FragU af[4];
    #pragma unroll
    for (int ks = 0; ks < 4; ++ks) {
        const int up0 = ks * 16 + 2 * q;
        const int o   = og * 16 + l15;
        af[ks].u[0] = atb[(up0)     * 64 + o];
        af[ks].u[1] = atb[(up0 + 1) * 64 + o];
        af[ks].u[2] = atb[(up0 + 8) * 64 + o];
        af[ks].u[3] = atb[(up0 + 9) * 64 + o];
    }
    const float4 bias = *(const float4*)&bout[og * 16 + q * 4];

    asm volatile("s_waitcnt vmcnt(0)" ::: "memory");
    __syncthreads();               // xbh staged by all waves

    const long i0g = (long)(blk * K1_TPB - b * NTILES) * 64;
    #pragma unroll 1
    for (int tt = 0; tt < K1_TPB; ++tt) {
        const long i0 = i0g + tt * 64;

        // phase 1 + softmax, per px-block ni
        #pragma unroll
        for (int ni = 0; ni < 4; ++ni) {
            const int rb = (tt * 64 + ni * 16 + l15) * 32;
            FragU bh[2];
            #pragma unroll
            for (int ks = 0; ks < 2; ++ks) {
                const int c0 = (ks * 16 + 2 * q) ^ yv;
                const int c1 = (ks * 16 + 2 * q + 8) ^ yv;
                uint2 t0 = *(const uint2*)&xbh[rb + c0];
                uint2 t1 = *(const uint2*)&xbh[rb + c1];
                bh[ks].u[0] = t0.x; bh[ks].u[1] = t0.y;
                bh[ks].u[2] = t1.x; bh[ks].u[3] = t1.y;
            }
            f32x4 a0 = (f32x4)0.f, a1 = (f32x4)0.f;
            #pragma unroll
            for (int ks = 0; ks < 2; ++ks) {
                a0 = MFMA(wh[0][ks].v, bh[ks].v, a0);
                a1 = MFMA(wh[1][ks].v, bh[ks].v, a1);
            }
            // softmax over head og's 32 rows for this lane's px column
            float mx = a0[0];
            #pragma unroll
            for (int j = 1; j < 4; ++j) mx = fmaxf(mx, a0[j]);
            #pragma unroll
            for (int j = 0; j < 4; ++j) mx = fmaxf(mx, a1[j]);
            mx = fmaxf(mx, __shfl_xor(mx, 16));
            mx = fmaxf(mx, __shfl_xor(mx, 32));
            float e0[4], e1[4], sm = 0.f;
            #pragma unroll
            for (int j = 0; j < 4; ++j) { e0[j] = __expf(a0[j] - mx); sm += e0[j]; }
            #pragma unroll
            for (int j = 0; j < 4; ++j) { e1[j] = __expf(a1[j] - mx); sm += e1[j]; }
            sm += __shfl_xor(sm, 16);
            sm += __shfl_xor(sm, 32);
            const float inv = 1.0f / sm;
            const int px = ni * 16 + l15;
            const int Xq = (px & 7) << 3;          // u16-unit swizzle
            u32* qbw = (u32*)qb;
            const int b0 = (px * 128 + ((og * 32 + q * 4) ^ Xq)) >> 1;
            const int b1 = (px * 128 + ((og * 32 + 16 + q * 4) ^ Xq)) >> 1;
            *(uint2*)&qbw[b0] = make_uint2(pk2(e0[0] * inv, e0[1] * inv),
                                           pk2(e0[2] * inv, e0[3] * inv));
            *(uint2*)&qbw[b1] = make_uint2(pk2(e1[0] * inv, e1[1] * inv),
                                           pk2(e1[2] * inv, e1[3] * inv));
        }
        __syncthreads();               // qb ready

        // phase 3: out = A^T qsm + bias
        const u32* qb32 = (const u32*)qb;
        #pragma unroll
        for (int ni = 0; ni < 4; ++ni) {
            const int px = ni * 16 + l15;
            const int rb = px * 64;
            f32x4 a3 = (f32x4)0.f;
            #pragma unroll
            for (int ks = 0; ks < 4; ++ks) {
                const int c0 = (ks * 16 + 2 * q) ^ yv;
                const int c1 = (ks * 16 + 2 * q + 8) ^ yv;
                uint2 t0 = *(const uint2*)&qb32[rb + c0];
                uint2 t1 = *(const uint2*)&qb32[rb + c1];
                FragU bq;
                bq.u[0] = t0.x; bq.u[1] = t0.y; bq.u[2] = t1.x; bq.u[3] = t1.y;
                a3 = MFMA(af[ks].v, bq.v, a3);
            }
            #pragma unroll
            for (int j = 0; j < 4; ++j)
                out[((long)b * 64 + og * 16 + q * 4 + j) * NPIX + i0 + px] = a3[j] + bias[j];
        }
        __syncthreads();               // qb consumed before next tile's writes
    }
}

extern "C" void kernel_launch(void* const* d_in, const int* in_sizes, int n_in,
                              void* d_out, int out_size, void* d_ws, size_t ws_size,
                              hipStream_t stream) {
    (void)in_sizes; (void)n_in; (void)out_size;
    const float* x     = (const float*)d_in[0];
    const float* w_qkv = (const float*)d_in[1];
    const float* w_out = (const float*)d_in[2];
    const float* b_out = (const float*)d_in[3];
    float* out = (float*)d_out;
    float* ws  = (float*)d_ws;

    const size_t need_part = ((size_t)WS_PART + (size_t)K1_BLOCKS * PART_STRIDE) * 4;
    const int usePart = (ws_size >= need_part) ? 1 : 0;
    int R = 8;
    const size_t need_r8 = ((size_t)WS_PART + (size_t)2 * 8 * PART_STRIDE) * 4;
    if (!usePart && ws_size < need_r8) R = 1;
    const int PB = usePart ? K1_BLOCKS : 2 * R;
    float* part = ws + WS_PART;

    if (!usePart)
        hipMemsetAsync(part, 0, (size_t)PB * PART_STRIDE * 4, stream);
    hipLaunchKernelGGL(k1_ctx, dim3(K1_BLOCKS), dim3(256), 0, stream,
                       x, w_qkv, ws, usePart, R);
    hipLaunchKernelGGL(k1b_reduce, dim3(33 * 2 * NSLICE), dim3(128), 0, stream, ws, PB);
    hipLaunchKernelGGL(k2_prepA, dim3(16), dim3(256), 0, stream, w_out, ws);
    hipLaunchKernelGGL(k3_out, dim3(K1_BLOCKS), dim3(256), 0, stream,
                       x, w_qkv, b_out, ws, out);
}